// Round 6
// baseline (259.599 us; speedup 1.0000x reference)
//
#include <hip/hip_runtime.h>
#include <math.h>

#define B_ 4
#define C_ 128
#define HW_ 16384
#define P_ 65536
#define S_ 8388608   // B*C*H*W elements
#define CPG 8        // channels per group (128/16)

typedef unsigned short u16;
typedef __attribute__((ext_vector_type(8))) short short8;
typedef __attribute__((ext_vector_type(4))) float f32x4;

__device__ __forceinline__ float sigmoidf_(float x){ return 1.f/(1.f+__expf(-x)); }
__device__ __forceinline__ float siluf_(float x){ return x*sigmoidf_(x); }
__device__ __forceinline__ u16 f2bf(float f){
  unsigned x = __float_as_uint(f);
  return (u16)((x + 0x7fffu + ((x >> 16) & 1u)) >> 16);
}
__device__ __forceinline__ float b2f(u16 u){ return __uint_as_float(((unsigned)u) << 16); }

// Build wfrag (dyn_w in MFMA A-fragment order), bperm, wgbf, wobf, wibf, stats=0.
__global__ __launch_bounds__(256) void prep_kernel(const float* __restrict__ dyn_w,
    const float* __restrict__ dyn_b, const float* __restrict__ w_gate,
    const float* __restrict__ w_out, const float* __restrict__ w_in,
    u16* __restrict__ wfrag, float* __restrict__ bperm, u16* __restrict__ wgbf,
    u16* __restrict__ wobf, u16* __restrict__ wibf, float* __restrict__ stats)
{
  int idx = blockIdx.x*256 + threadIdx.x;
  if (idx < 262144) {
    int e = idx & 7, lane = (idx >> 3) & 63, kk = (idx >> 9) & 3;
    int ct = (idx >> 11) & 31, d = idx >> 16;
    int m = lane & 15, kg = lane >> 4;
    int col = ct*16 + m;
    int c = col >> 2, f = col & 3;
    int k = kk*32 + kg*8 + e;
    wfrag[idx] = f2bf(dyn_w[(size_t)((d*512) + f*128 + c)*128 + k]);
  } else if (idx < 264192) {
    int i2 = idx - 262144;
    int op = i2 & 511, d = i2 >> 9;
    bperm[i2] = dyn_b[d*512 + (op & 3)*128 + (op >> 2)];
  } else if (idx < 280576) {
    wgbf[idx - 264192] = f2bf(w_gate[idx - 264192]);
  } else if (idx < 296960) {
    wobf[idx - 280576] = f2bf(w_out[idx - 280576]);
  } else if (idx < 313344) {
    wibf[idx - 296960] = f2bf(w_in[idx - 296960]);
  } else if (idx < 313600) {
    stats[idx - 313344] = 0.f;
  }
}

// Transpose+convert: x fp32 [B][128][16384] -> xT bf16 [B*16384][128].
__global__ __launch_bounds__(256) void xpose(const float* __restrict__ x,
    u16* __restrict__ xT)
{
  __shared__ u16 tile[32*132];   // stride 132 u16 = 264 B (66 words, coprime-ish w/ 32)
  int b = blockIdx.y;
  int p0 = blockIdx.x << 5;
  int t = threadIdx.x;
  const float* xb = x + ((size_t)b << 21);
  #pragma unroll
  for (int i = 0; i < 16; ++i) {
    int idx = i*256 + t;
    int c = idx >> 5, pp = idx & 31;
    tile[pp*132 + c] = f2bf(xb[(size_t)c*HW_ + p0 + pp]);
  }
  __syncthreads();
  u16* ob = xT + ((size_t)b << 21) + ((size_t)p0 << 7);
  #pragma unroll
  for (int i = 0; i < 2; ++i) {
    int slot = i*256 + t;
    int pp = slot >> 4, j = slot & 15;
    uint2 v0 = *(const uint2*)((const char*)tile + pp*264 + j*16);
    uint2 v1 = *(const uint2*)((const char*)tile + pp*264 + j*16 + 8);
    uint4 o; o.x = v0.x; o.y = v0.y; o.z = v1.x; o.w = v1.y;
    *(uint4*)(ob + (pp << 7) + (j << 3)) = o;
  }
}

// in_proj MFMA NT GEMM with fused GN1 stats: X=xT bf16 [P][128], Wm=wibf [128][128],
// Out=xp_raw bf16 [P][128]; atomicAdd per-(b,group) sum/sumsq into stats[0:128].
__global__ __launch_bounds__(256) void mfma_inproj(const u16* __restrict__ X,
    const u16* __restrict__ Wm, u16* __restrict__ Out, float* __restrict__ stats)
{
  int wv = threadIdx.x >> 6, lane = threadIdx.x & 63;
  int pt = blockIdx.x*256 + wv*64;
  int ot = blockIdx.y*64;
  int b = blockIdx.x >> 6;
  int m = lane & 15, kg = lane >> 4;
  short8 Af[4][4];
  #pragma unroll
  for (int rt = 0; rt < 4; ++rt) {
    const u16* ar = X + ((size_t)(pt + rt*16 + m) << 7) + kg*8;
    #pragma unroll
    for (int kk = 0; kk < 4; ++kk)
      Af[rt][kk] = *(const short8*)(ar + kk*32);
  }
  f32x4 acc[4][4];
  #pragma unroll
  for (int rt = 0; rt < 4; ++rt)
    #pragma unroll
    for (int ct = 0; ct < 4; ++ct)
      acc[rt][ct] = (f32x4){0.f, 0.f, 0.f, 0.f};
  #pragma unroll
  for (int ct = 0; ct < 4; ++ct) {
    const u16* wr = Wm + ((size_t)(ot + ct*16 + m) << 7) + kg*8;
    short8 Bf[4];
    #pragma unroll
    for (int kk = 0; kk < 4; ++kk)
      Bf[kk] = *(const short8*)(wr + kk*32);
    #pragma unroll
    for (int rt = 0; rt < 4; ++rt)
      #pragma unroll
      for (int kk = 0; kk < 4; ++kk)
        acc[rt][ct] = __builtin_amdgcn_mfma_f32_16x16x32_bf16(Af[rt][kk], Bf[kk], acc[rt][ct], 0, 0, 0);
  }
  #pragma unroll
  for (int ct = 0; ct < 4; ++ct) {
    float s = 0.f, q = 0.f;
    #pragma unroll
    for (int rt = 0; rt < 4; ++rt) {
      #pragma unroll
      for (int r = 0; r < 4; ++r) {
        int row = pt + rt*16 + kg*4 + r;
        int col = ot + ct*16 + m;
        float v = acc[rt][ct][r];
        Out[(size_t)row*128 + col] = f2bf(v);
        s += v; q += v*v;
      }
    }
    s += __shfl_xor(s, 16); q += __shfl_xor(q, 16);
    s += __shfl_xor(s, 32); q += __shfl_xor(q, 32);
    s += __shfl_xor(s, 1);  q += __shfl_xor(q, 1);
    s += __shfl_xor(s, 2);  q += __shfl_xor(q, 2);
    s += __shfl_xor(s, 4);  q += __shfl_xor(q, 4);
    if ((lane & 0x37) == 0) {          // lane 0 or 8
      int g = (ot + ct*16 + (lane & 8)) >> 3;
      atomicAdd(&stats[b*16 + g], s);
      atomicAdd(&stats[64 + b*16 + g], q);
    }
  }
}

// MFMA NT GEMM: X bf16 [P][128], W bf16 [OO][128], Out bf16 [P][OO], K=128.
template<int OO, int BIAS, int SIG>
__global__ __launch_bounds__(256) void mfma_nt(const u16* __restrict__ X,
    const u16* __restrict__ Wm, const float* __restrict__ bias, u16* __restrict__ Out)
{
  int wv = threadIdx.x >> 6, lane = threadIdx.x & 63;
  int pt = blockIdx.x*256 + wv*64;
  int ot = blockIdx.y*64;
  int m = lane & 15, kg = lane >> 4;
  short8 Af[4][4];
  #pragma unroll
  for (int rt = 0; rt < 4; ++rt) {
    const u16* ar = X + ((size_t)(pt + rt*16 + m) << 7) + kg*8;
    #pragma unroll
    for (int kk = 0; kk < 4; ++kk)
      Af[rt][kk] = *(const short8*)(ar + kk*32);
  }
  f32x4 acc[4][4];
  #pragma unroll
  for (int rt = 0; rt < 4; ++rt)
    #pragma unroll
    for (int ct = 0; ct < 4; ++ct)
      acc[rt][ct] = (f32x4){0.f, 0.f, 0.f, 0.f};
  #pragma unroll
  for (int ct = 0; ct < 4; ++ct) {
    const u16* wr = Wm + ((size_t)(ot + ct*16 + m) << 7) + kg*8;
    short8 Bf[4];
    #pragma unroll
    for (int kk = 0; kk < 4; ++kk)
      Bf[kk] = *(const short8*)(wr + kk*32);
    #pragma unroll
    for (int rt = 0; rt < 4; ++rt)
      #pragma unroll
      for (int kk = 0; kk < 4; ++kk)
        acc[rt][ct] = __builtin_amdgcn_mfma_f32_16x16x32_bf16(Af[rt][kk], Bf[kk], acc[rt][ct], 0, 0, 0);
  }
  #pragma unroll
  for (int ct = 0; ct < 4; ++ct) {
    float bv = BIAS ? bias[ot + ct*16 + m] : 0.f;
    #pragma unroll
    for (int rt = 0; rt < 4; ++rt) {
      #pragma unroll
      for (int r = 0; r < 4; ++r) {
        int row = pt + rt*16 + kg*4 + r;
        int col = ot + ct*16 + m;
        float v = acc[rt][ct][r] + bv;
        if (SIG) v = sigmoidf_(v);
        Out[(size_t)row*OO + col] = f2bf(v);
      }
    }
  }
}

// Produce 16-pos coeff chunk into cs double buffer (bank-swizzled).
#define PRODUCE(NT, bufv, chunkv)  do { \
  int posg_ = (chunkv)*16 + m; int swp_ = (posg_ & 7) << 4; \
  short8 Bfr[4]; \
  _Pragma("unroll") for (int kk = 0; kk < 4; ++kk) \
    Bfr[kk] = *(const short8*)((char*)xs + posg_*256 + (((kk<<6)+(kg<<4)) ^ swp_)); \
  _Pragma("unroll") for (int ti = 0; ti < NT; ++ti) { \
    f32x4 acc = (f32x4){0.f,0.f,0.f,0.f}; \
    _Pragma("unroll") for (int kk = 0; kk < 4; ++kk) \
      acc = __builtin_amdgcn_mfma_f32_16x16x32_bf16(Af[ti][kk], Bfr[kk], acc, 0, 0, 0); \
    int colL_ = (tbase + ti)*16 + (kg<<2); \
    unsigned lo_ = (unsigned)f2bf(acc[0]) | ((unsigned)f2bf(acc[1])<<16); \
    unsigned hi_ = (unsigned)f2bf(acc[2]) | ((unsigned)f2bf(acc[3])<<16); \
    int byte_ = (((bufv)*2 + dw)<<14) + (m<<10) + ((colL_<<1) ^ ((m&7)<<4)); \
    *(uint2*)((char*)cs + byte_) = make_uint2(lo_, hi_); \
  } } while(0)

#define SCAN_STEP(s) { \
  float ar = b2f((u16)(cw[s].x & 0xffffu)) + bv.x; \
  float br = b2f((u16)(cw[s].x >> 16)) + bv.y; \
  float cr = b2f((u16)(cw[s].y & 0xffffu)) + bv.z; \
  float dr = b2f((u16)(cw[s].y >> 16)) + bv.w; \
  float aa = sigmoidf_(ar); \
  h = aa*h + br*xf[s]; \
  yv[s] = cr*h + dr*xf[s]; }

// Fused coeff-GEMM + bidirectional scan, wave-specialized, cs double-buffered,
// y accumulated in LDS (no per-phase global traffic).
// Block = 512 thr (8 waves): waves 0-3 = scanners (+4 W-tiles); waves 4-7 =
// producers (12 W-tiles). AXISW=1: lines along W, PART=0 (store out).
// AXISW=0: lines along H, PART=1 (coalesced global RMW add at end).
template<int AXISW, int PART>
__global__ __launch_bounds__(512, 2) void scan_fused(const u16* __restrict__ Abf,
    const u16* __restrict__ Wf, const float* __restrict__ bias,
    u16* __restrict__ fusedP)
{
  __shared__ __align__(16) u16 xs[128*128];      // 32 KB, swizzled byte ^ ((pos&7)<<4)
  __shared__ __align__(16) u16 cs[2][2][16*512]; // 64 KB: [buf][dir][16 pos][512 cols]
  __shared__ __align__(16) u16 ysL[128*128];     // 32 KB bf16 partial y [pos][ch]
  int line = blockIdx.x;
  int b = line >> 7, l = line & 127;
  int t = threadIdx.x;
  int wv = t >> 6, lane = t & 63;
  int m = lane & 15, kg = lane >> 4;
  int dw = (wv >> 1) & 1;    // this wave's coeff direction

  // stage xp tile for the line (128 pos x 128 ch)
  #pragma unroll
  for (int i = 0; i < 4; ++i) {
    int idx = i*512 + t;
    int pos = idx >> 4, j = idx & 15;
    size_t row = AXISW ? ((size_t)(b<<14) + (l<<7) + pos)
                       : ((size_t)(b<<14) + (pos<<7) + l);
    short8 v = *(const short8*)(Abf + (row<<7) + (j<<3));
    int byte = pos*256 + ((j*16) ^ ((pos&7)<<4));
    *(short8*)((char*)xs + byte) = v;
  }

  if (wv < 4) {
    // ---------- scanner + light producer ----------
    int tbase = (wv & 1) * 4;
    short8 Af[4][4];
    #pragma unroll
    for (int ti = 0; ti < 4; ++ti)
      #pragma unroll
      for (int kk = 0; kk < 4; ++kk)
        Af[ti][kk] = *(const short8*)(Wf + (size_t)(((dw*32 + tbase + ti)*4 + kk)*64 + lane)*8);
    __syncthreads();                       // xs ready
    PRODUCE(4, 0, dw ? 7 : 0);
    __syncthreads();                       // cs[0] ready

    int sd = dw;
    int sc = ((wv & 1) << 6) + lane;       // scan channel 0..127
    float4 bv = *(const float4*)(bias + (sd << 9) + (sc << 2));
    float h = 0.f;

    #pragma unroll 1
    for (int k = 0; k < 8; ++k) {
      if (k < 7) PRODUCE(4, (k+1)&1, dw ? (6-k) : (k+1));
      int chunk = sd ? (7-k) : k;
      int csb = (((k&1)*2 + sd) << 14);
      uint2 cw[16];
      #pragma unroll
      for (int s = 0; s < 16; ++s)
        cw[s] = *(const uint2*)((char*)cs + csb + (s<<10) + ((sc<<3) ^ ((s&7)<<4)));
      float xf[16];
      #pragma unroll
      for (int s = 0; s < 16; ++s) {
        int pos = (chunk<<4) + s;
        xf[s] = b2f(*(const u16*)((char*)xs + pos*256 + ((sc<<1) ^ ((s&7)<<4))));
      }
      float yv[16];
      __builtin_amdgcn_s_setprio(1);
      if (sd == 0) {
        #pragma unroll
        for (int s = 0; s < 16; ++s) SCAN_STEP(s)
      } else {
        #pragma unroll
        for (int s = 15; s >= 0; --s) SCAN_STEP(s)
      }
      __builtin_amdgcn_s_setprio(0);
      u16* yrow = ysL + (chunk << 11) + sc;
      if (k <= 3) {
        #pragma unroll
        for (int s = 0; s < 16; ++s) yrow[s << 7] = f2bf(0.25f*yv[s]);
      } else {
        #pragma unroll
        for (int s = 0; s < 16; ++s) {
          float o = b2f(yrow[s << 7]);
          yrow[s << 7] = f2bf(o + 0.25f*yv[s]);
        }
      }
      __syncthreads();
    }
  } else {
    // ---------- heavy producer ----------
    int tbase = 8 + (wv & 1) * 12;
    short8 Af[12][4];
    #pragma unroll
    for (int ti = 0; ti < 12; ++ti)
      #pragma unroll
      for (int kk = 0; kk < 4; ++kk)
        Af[ti][kk] = *(const short8*)(Wf + (size_t)(((dw*32 + tbase + ti)*4 + kk)*64 + lane)*8);
    __syncthreads();                       // xs ready
    PRODUCE(12, 0, dw ? 7 : 0);
    __syncthreads();                       // cs[0] ready
    #pragma unroll 1
    for (int k = 0; k < 8; ++k) {
      if (k < 7) PRODUCE(12, (k+1)&1, dw ? (6-k) : (k+1));
      __syncthreads();
    }
  }

  // cooperative coalesced writeout: 2048 short8 slots
  #pragma unroll
  for (int r = 0; r < 4; ++r) {
    int slot = r*512 + t;
    int pos = slot >> 4, j = slot & 15;
    short8 v = *(const short8*)(ysL + (pos << 7) + (j << 3));
    size_t rowg = AXISW ? ((size_t)(b<<14) + (l<<7) + pos)
                        : ((size_t)(b<<14) + (pos<<7) + l);
    u16* op = fusedP + (rowg << 7) + (j << 3);
    if (PART) {
      short8 o = *(const short8*)op;
      short8 rr;
      #pragma unroll
      for (int i = 0; i < 8; ++i) rr[i] = (short)f2bf(b2f((u16)v[i]) + b2f((u16)o[i]));
      *(short8*)op = rr;
    } else {
      *(short8*)op = v;
    }
  }
}

// GroupNorm stats over bf16 channels-last.
__global__ __launch_bounds__(256) void gn_stats_bf(const u16* __restrict__ X,
    float* __restrict__ stats)
{
  int bg = blockIdx.x, chunk = blockIdx.y;
  int b = bg >> 4, g = bg & 15;
  int t = threadIdx.x;
  int c = t & 7, pr = t >> 3;
  const u16* base = X + ((size_t)b << 21) + (g << 3) + c;
  int p0 = chunk << 10;
  float s = 0.f, s2 = 0.f;
  for (int i = 0; i < 32; ++i) {
    float v = b2f(base[(size_t)(p0 + (i << 5) + pr) << 7]);
    s += v; s2 += v*v;
  }
  #pragma unroll
  for (int off = 32; off; off >>= 1) { s += __shfl_down(s, off); s2 += __shfl_down(s2, off); }
  __shared__ float ls[8];
  int wv = t >> 6, lane = t & 63;
  if (lane == 0) { ls[wv] = s; ls[4 + wv] = s2; }
  __syncthreads();
  if (t == 0) {
    atomicAdd(&stats[bg], ls[0]+ls[1]+ls[2]+ls[3]);
    atomicAdd(&stats[64+bg], ls[4]+ls[5]+ls[6]+ls[7]);
  }
}

// Apply GN1 + SiLU: read bf16, write bf16.
__global__ __launch_bounds__(256) void gn_apply(const u16* __restrict__ X,
    const float* __restrict__ stats, const float* __restrict__ gamma,
    const float* __restrict__ beta, u16* __restrict__ Xb)
{
  int i4 = blockIdx.x*256 + threadIdx.x;
  size_t base = (size_t)i4 << 2;
  int c4 = (int)(base & 127);
  size_t p = base >> 7;
  int b = (int)(p >> 14);
  int g = c4 >> 3;
  const float cnt = (float)(CPG*HW_);
  float mu = stats[b*16+g]/cnt;
  float var = stats[64+b*16+g]/cnt - mu*mu;
  float rs = rsqrtf(var + 1e-5f);
  ushort4 v = *(const ushort4*)(X + base);
  ushort4 o;
  o.x = f2bf(siluf_((b2f(v.x)-mu)*rs*gamma[c4+0]+beta[c4+0]));
  o.y = f2bf(siluf_((b2f(v.y)-mu)*rs*gamma[c4+1]+beta[c4+1]));
  o.z = f2bf(siluf_((b2f(v.z)-mu)*rs*gamma[c4+2]+beta[c4+2]));
  o.w = f2bf(siluf_((b2f(v.w)-mu)*rs*gamma[c4+3]+beta[c4+3]));
  *(ushort4*)(Xb + base) = o;
}

// Depthwise 3x3 with fused gate multiply: z = dw3x3(fused * gate), bf16 in/out.
__global__ __launch_bounds__(256) void dwconv(const u16* __restrict__ Z,
    const u16* __restrict__ G, const float* __restrict__ K9, u16* __restrict__ Outp)
{
  __shared__ float kk[1152];
  int t = threadIdx.x;
  for (int i = t; i < 1152; i += 256) kk[i] = K9[i];
  __syncthreads();
  int i4 = blockIdx.x*256 + t;
  size_t base = (size_t)i4 << 2;
  int c0 = (int)(base & 127);
  size_t p = base >> 7;
  int w = (int)(p & 127), h = (int)((p >> 7) & 127), b = (int)(p >> 14);
  float4 acc = make_float4(0.f,0.f,0.f,0.f);
  #pragma unroll
  for (int di = 0; di < 3; ++di) {
    int hy = h + di - 1;
    if ((unsigned)hy > 127u) continue;
    #pragma unroll
    for (int dj = 0; dj < 3; ++dj) {
      int wx = w + dj - 1;
      if ((unsigned)wx > 127u) continue;
      size_t p2 = ((size_t)b << 14) + (hy << 7) + wx;
      ushort4 zv = *(const ushort4*)(Z + (p2 << 7) + c0);
      ushort4 gv = *(const ushort4*)(G + (p2 << 7) + c0);
      int o = di*3 + dj;
      acc.x += b2f(zv.x) * b2f(gv.x) * kk[c0*9 + o];
      acc.y += b2f(zv.y) * b2f(gv.y) * kk[(c0+1)*9 + o];
      acc.z += b2f(zv.z) * b2f(gv.z) * kk[(c0+2)*9 + o];
      acc.w += b2f(zv.w) * b2f(gv.w) * kk[(c0+3)*9 + o];
    }
  }
  ushort4 ov;
  ov.x = f2bf(acc.x); ov.y = f2bf(acc.y); ov.z = f2bf(acc.z); ov.w = f2bf(acc.w);
  *(ushort4*)(Outp + base) = ov;
}

// GN2 apply + SiLU + transpose to channels-first fp32 output. Input bf16.
__global__ __launch_bounds__(256) void gn_final(const u16* __restrict__ Z,
    const float* __restrict__ stats, const float* __restrict__ gamma,
    const float* __restrict__ beta, float* __restrict__ out)
{
  __shared__ float ls[32][129];
  int w0 = blockIdx.x << 5, hh = blockIdx.y, b = blockIdx.z;
  size_t p0 = ((size_t)b << 14) + (hh << 7) + w0;
  int t = threadIdx.x;
  const float cnt = (float)(CPG*HW_);
  #pragma unroll
  for (int i = 0; i < 4; ++i) {
    int l = t + i*256;
    int row = l >> 5, c4 = (l & 31) << 2;
    ushort4 v = *(const ushort4*)(Z + ((p0 + row) << 7) + c4);
    int g = c4 >> 3;
    float mu = stats[b*16+g]/cnt;
    float var = stats[64+b*16+g]/cnt - mu*mu;
    float rs = rsqrtf(var + 1e-5f);
    float vals[4] = {b2f(v.x), b2f(v.y), b2f(v.z), b2f(v.w)};
    #pragma unroll
    for (int j = 0; j < 4; ++j) {
      float nv = (vals[j]-mu)*rs*gamma[c4+j] + beta[c4+j];
      ls[row][c4+j] = siluf_(nv);
    }
  }
  __syncthreads();
  int ww = t & 31, c0 = t >> 5;
  #pragma unroll
  for (int cc = c0; cc < 128; cc += 8) {
    out[(((size_t)(b*128 + cc)) << 14) + (hh << 7) + (w0 + ww)] = ls[ww][cc];
  }
}

extern "C" void kernel_launch(void* const* d_in, const int* in_sizes, int n_in,
                              void* d_out, int out_size, void* d_ws, size_t ws_size,
                              hipStream_t stream)
{
  (void)in_sizes; (void)n_in; (void)out_size; (void)ws_size;
  const float* x      = (const float*)d_in[0];
  const float* w_in   = (const float*)d_in[1];
  const float* g1g    = (const float*)d_in[2];
  const float* g1b    = (const float*)d_in[3];
  const float* w_gate = (const float*)d_in[4];
  const float* b_gate = (const float*)d_in[5];
  const float* dyn_w  = (const float*)d_in[6];
  const float* dyn_b  = (const float*)d_in[7];
  const float* dwk    = (const float*)d_in[8];
  const float* w_out  = (const float*)d_in[9];
  const float* g2g    = (const float*)d_in[10];
  const float* g2b    = (const float*)d_in[11];
  float* out = (float*)d_out;

  char* p = (char*)d_ws;
  u16*   xT     = (u16*)p;              p += (size_t)S_*2;   // x transposed bf16; later Zdw
  u16*   xpr    = (u16*)p;              p += (size_t)S_*2;   // xp_raw bf16; later Zout
  u16*   Abf    = (u16*)p;              p += (size_t)S_*2;   // xp (post GN1+SiLU) bf16
  u16*   fusedP = (u16*)p;              p += (size_t)S_*2;   // fused partial/final bf16
  u16*   Gbf    = (u16*)p;              p += (size_t)S_*2;   // gate bf16
  u16*   wfrag  = (u16*)p;              p += (size_t)262144*2;
  u16*   wgbf   = (u16*)p;              p += (size_t)16384*2;
  u16*   wobf   = (u16*)p;              p += (size_t)16384*2;
  u16*   wibf   = (u16*)p;              p += (size_t)16384*2;
  float* bperm  = (float*)p;            p += (size_t)2048*4;
  float* stats  = (float*)p;            p += (size_t)256*4;
  u16*   Zdw    = xT;                   // alias (xT dead after mfma_inproj)
  u16*   Zout   = xpr;                  // alias (xp_raw dead after gn_apply)

  prep_kernel<<<1225, 256, 0, stream>>>(dyn_w, dyn_b, w_gate, w_out, w_in,
                                        wfrag, bperm, wgbf, wobf, wibf, stats);
  xpose<<<dim3(512, 4), 256, 0, stream>>>(x, xT);
  mfma_inproj<<<dim3(256, 2), 256, 0, stream>>>(xT, wibf, xpr, stats);
  gn_apply<<<8192, 256, 0, stream>>>(xpr, stats, g1g, g1b, Abf);

  scan_fused<1,0><<<512, 512, 0, stream>>>(Abf, wfrag, bperm, fusedP);
  scan_fused<0,1><<<512, 512, 0, stream>>>(Abf, wfrag + 131072, bperm + 1024, fusedP);

  mfma_nt<128,1,1><<<dim3(256, 2), 256, 0, stream>>>(Abf, wgbf, b_gate, Gbf);
  dwconv<<<8192, 256, 0, stream>>>(fusedP, Gbf, dwk, Zdw);
  mfma_nt<128,0,0><<<dim3(256, 2), 256, 0, stream>>>(Zdw, wobf, nullptr, Zout);
  gn_stats_bf<<<dim3(64, 16), 256, 0, stream>>>(Zout, stats + 128);
  gn_final<<<dim3(4, 128, 4), 256, 0, stream>>>(Zout, stats + 128, g2g, g2b, out);
}

// Round 7
// 236.231 us; speedup vs baseline: 1.0989x; 1.0989x over previous
//
#include <hip/hip_runtime.h>
#include <math.h>

#define B_ 4
#define C_ 128
#define HW_ 16384
#define P_ 65536
#define S_ 8388608   // B*C*H*W elements
#define CPG 8        // channels per group (128/16)

typedef unsigned short u16;
typedef __attribute__((ext_vector_type(8))) short short8;
typedef __attribute__((ext_vector_type(4))) float f32x4;

__device__ __forceinline__ float sigmoidf_(float x){ return 1.f/(1.f+__expf(-x)); }
__device__ __forceinline__ float siluf_(float x){ return x*sigmoidf_(x); }
__device__ __forceinline__ u16 f2bf(float f){
  unsigned x = __float_as_uint(f);
  return (u16)((x + 0x7fffu + ((x >> 16) & 1u)) >> 16);
}
__device__ __forceinline__ float b2f(u16 u){ return __uint_as_float(((unsigned)u) << 16); }

// Build wfrag (dyn_w in MFMA A-fragment order), bperm, wgbf, wobf, wibf, stats=0.
__global__ __launch_bounds__(256) void prep_kernel(const float* __restrict__ dyn_w,
    const float* __restrict__ dyn_b, const float* __restrict__ w_gate,
    const float* __restrict__ w_out, const float* __restrict__ w_in,
    u16* __restrict__ wfrag, float* __restrict__ bperm, u16* __restrict__ wgbf,
    u16* __restrict__ wobf, u16* __restrict__ wibf, float* __restrict__ stats)
{
  int idx = blockIdx.x*256 + threadIdx.x;
  if (idx < 262144) {
    int e = idx & 7, lane = (idx >> 3) & 63, kk = (idx >> 9) & 3;
    int ct = (idx >> 11) & 31, d = idx >> 16;
    int m = lane & 15, kg = lane >> 4;
    int col = ct*16 + m;
    int c = col >> 2, f = col & 3;
    int k = kk*32 + kg*8 + e;
    wfrag[idx] = f2bf(dyn_w[(size_t)((d*512) + f*128 + c)*128 + k]);
  } else if (idx < 264192) {
    int i2 = idx - 262144;
    int op = i2 & 511, d = i2 >> 9;
    bperm[i2] = dyn_b[d*512 + (op & 3)*128 + (op >> 2)];
  } else if (idx < 280576) {
    wgbf[idx - 264192] = f2bf(w_gate[idx - 264192]);
  } else if (idx < 296960) {
    wobf[idx - 280576] = f2bf(w_out[idx - 280576]);
  } else if (idx < 313344) {
    wibf[idx - 296960] = f2bf(w_in[idx - 296960]);
  } else if (idx < 313600) {
    stats[idx - 313344] = 0.f;
  }
}

// Transpose+convert: x fp32 [B][128][16384] -> xT bf16 [B*16384][128].
__global__ __launch_bounds__(256) void xpose(const float* __restrict__ x,
    u16* __restrict__ xT)
{
  __shared__ u16 tile[32*132];
  int b = blockIdx.y;
  int p0 = blockIdx.x << 5;
  int t = threadIdx.x;
  const float* xb = x + ((size_t)b << 21);
  #pragma unroll
  for (int i = 0; i < 16; ++i) {
    int idx = i*256 + t;
    int c = idx >> 5, pp = idx & 31;
    tile[pp*132 + c] = f2bf(xb[(size_t)c*HW_ + p0 + pp]);
  }
  __syncthreads();
  u16* ob = xT + ((size_t)b << 21) + ((size_t)p0 << 7);
  #pragma unroll
  for (int i = 0; i < 2; ++i) {
    int slot = i*256 + t;
    int pp = slot >> 4, j = slot & 15;
    uint2 v0 = *(const uint2*)((const char*)tile + pp*264 + j*16);
    uint2 v1 = *(const uint2*)((const char*)tile + pp*264 + j*16 + 8);
    uint4 o; o.x = v0.x; o.y = v0.y; o.z = v1.x; o.w = v1.y;
    *(uint4*)(ob + (pp << 7) + (j << 3)) = o;
  }
}

// MFMA NT GEMM, O=128, LDS-staged coalesced output.
// X bf16 [P][128], Wm bf16 [128][128], Out bf16 [P][128].
// Grid: P/64 blocks; block 256 thr / 4 waves. Wave w: cols 32w..32w+31, rows pt..pt+63.
template<int BIAS, int SIG>
__global__ __launch_bounds__(256) void mfma_nt128(const u16* __restrict__ X,
    const u16* __restrict__ Wm, const float* __restrict__ bias, u16* __restrict__ Out)
{
  __shared__ __align__(16) u16 st[64*136];   // pad to 136 u16 (272 B, 16B-aligned rows)
  int t = threadIdx.x;
  int wv = t >> 6, lane = t & 63;
  int m = lane & 15, kg = lane >> 4;
  int pt = blockIdx.x << 6;

  short8 Af[4][4];
  #pragma unroll
  for (int rt = 0; rt < 4; ++rt) {
    const u16* ar = X + ((size_t)(pt + rt*16 + m) << 7) + kg*8;
    #pragma unroll
    for (int kk = 0; kk < 4; ++kk)
      Af[rt][kk] = *(const short8*)(ar + kk*32);
  }
  #pragma unroll
  for (int ct2 = 0; ct2 < 2; ++ct2) {
    int ot = wv*32 + ct2*16;
    const u16* wr = Wm + ((size_t)(ot + m) << 7) + kg*8;
    short8 Bf[4];
    #pragma unroll
    for (int kk = 0; kk < 4; ++kk)
      Bf[kk] = *(const short8*)(wr + kk*32);
    f32x4 acc[4];
    #pragma unroll
    for (int rt = 0; rt < 4; ++rt) acc[rt] = (f32x4){0.f,0.f,0.f,0.f};
    #pragma unroll
    for (int rt = 0; rt < 4; ++rt)
      #pragma unroll
      for (int kk = 0; kk < 4; ++kk)
        acc[rt] = __builtin_amdgcn_mfma_f32_16x16x32_bf16(Af[rt][kk], Bf[kk], acc[rt], 0, 0, 0);
    float bv = BIAS ? bias[ot + m] : 0.f;
    #pragma unroll
    for (int rt = 0; rt < 4; ++rt) {
      #pragma unroll
      for (int r = 0; r < 4; ++r) {
        float v = acc[rt][r] + bv;
        if (SIG) v = sigmoidf_(v);
        st[(rt*16 + kg*4 + r)*136 + ot + m] = f2bf(v);
      }
    }
  }
  __syncthreads();
  // coalesced writeout: 64 rows x 128 cols = 1024 short8 chunks
  #pragma unroll
  for (int i = 0; i < 4; ++i) {
    int slot = i*256 + t;
    int row = slot >> 4, j = slot & 15;
    short8 v = *(const short8*)(st + row*136 + (j << 3));
    *(short8*)(Out + ((size_t)(pt + row) << 7) + (j << 3)) = v;
  }
}

// Produce 16-pos coeff chunk into cs double buffer (bank-swizzled).
#define PRODUCE(NT, bufv, chunkv)  do { \
  int posg_ = (chunkv)*16 + m; int swp_ = (posg_ & 7) << 4; \
  short8 Bfr[4]; \
  _Pragma("unroll") for (int kk = 0; kk < 4; ++kk) \
    Bfr[kk] = *(const short8*)((char*)xs + posg_*256 + (((kk<<6)+(kg<<4)) ^ swp_)); \
  _Pragma("unroll") for (int ti = 0; ti < NT; ++ti) { \
    f32x4 acc = (f32x4){0.f,0.f,0.f,0.f}; \
    _Pragma("unroll") for (int kk = 0; kk < 4; ++kk) \
      acc = __builtin_amdgcn_mfma_f32_16x16x32_bf16(Af[ti][kk], Bfr[kk], acc, 0, 0, 0); \
    int colL_ = (tbase + ti)*16 + (kg<<2); \
    unsigned lo_ = (unsigned)f2bf(acc[0]) | ((unsigned)f2bf(acc[1])<<16); \
    unsigned hi_ = (unsigned)f2bf(acc[2]) | ((unsigned)f2bf(acc[3])<<16); \
    int byte_ = (((bufv)*2 + dw)<<14) + (m<<10) + ((colL_<<1) ^ ((m&7)<<4)); \
    *(uint2*)((char*)cs + byte_) = make_uint2(lo_, hi_); \
  } } while(0)

#define SCAN_STEP(s) { \
  float ar = b2f((u16)(cw[s].x & 0xffffu)) + bv.x; \
  float br = b2f((u16)(cw[s].x >> 16)) + bv.y; \
  float cr = b2f((u16)(cw[s].y & 0xffffu)) + bv.z; \
  float dr = b2f((u16)(cw[s].y >> 16)) + bv.w; \
  float aa = sigmoidf_(ar); \
  h = aa*h + br*xf[s]; \
  yv[s] = cr*h + dr*xf[s]; }

// Fused coeff-GEMM + bidirectional scan, wave-specialized, cs double-buffered,
// y accumulated in LDS. Block = 512 thr (8 waves).
template<int AXISW, int PART>
__global__ __launch_bounds__(512, 2) void scan_fused(const u16* __restrict__ Abf,
    const u16* __restrict__ Wf, const float* __restrict__ bias,
    u16* __restrict__ fusedP)
{
  __shared__ __align__(16) u16 xs[128*128];      // 32 KB, swizzled byte ^ ((pos&7)<<4)
  __shared__ __align__(16) u16 cs[2][2][16*512]; // 64 KB: [buf][dir][16 pos][512 cols]
  __shared__ __align__(16) u16 ysL[128*128];     // 32 KB bf16 partial y [pos][ch]
  int line = blockIdx.x;
  int b = line >> 7, l = line & 127;
  int t = threadIdx.x;
  int wv = t >> 6, lane = t & 63;
  int m = lane & 15, kg = lane >> 4;
  int dw = (wv >> 1) & 1;    // this wave's coeff direction

  // stage xp tile for the line (128 pos x 128 ch)
  #pragma unroll
  for (int i = 0; i < 4; ++i) {
    int idx = i*512 + t;
    int pos = idx >> 4, j = idx & 15;
    size_t row = AXISW ? ((size_t)(b<<14) + (l<<7) + pos)
                       : ((size_t)(b<<14) + (pos<<7) + l);
    short8 v = *(const short8*)(Abf + (row<<7) + (j<<3));
    int byte = pos*256 + ((j*16) ^ ((pos&7)<<4));
    *(short8*)((char*)xs + byte) = v;
  }

  if (wv < 4) {
    // ---------- scanner + light producer ----------
    int tbase = (wv & 1) * 4;
    short8 Af[4][4];
    #pragma unroll
    for (int ti = 0; ti < 4; ++ti)
      #pragma unroll
      for (int kk = 0; kk < 4; ++kk)
        Af[ti][kk] = *(const short8*)(Wf + (size_t)(((dw*32 + tbase + ti)*4 + kk)*64 + lane)*8);
    __syncthreads();                       // xs ready
    PRODUCE(4, 0, dw ? 7 : 0);
    __syncthreads();                       // cs[0] ready

    int sd = dw;
    int sc = ((wv & 1) << 6) + lane;       // scan channel 0..127
    float4 bv = *(const float4*)(bias + (sd << 9) + (sc << 2));
    float h = 0.f;

    #pragma unroll 1
    for (int k = 0; k < 8; ++k) {
      if (k < 7) PRODUCE(4, (k+1)&1, dw ? (6-k) : (k+1));
      int chunk = sd ? (7-k) : k;
      int csb = (((k&1)*2 + sd) << 14);
      uint2 cw[16];
      #pragma unroll
      for (int s = 0; s < 16; ++s)
        cw[s] = *(const uint2*)((char*)cs + csb + (s<<10) + ((sc<<3) ^ ((s&7)<<4)));
      float xf[16];
      #pragma unroll
      for (int s = 0; s < 16; ++s) {
        int pos = (chunk<<4) + s;
        xf[s] = b2f(*(const u16*)((char*)xs + pos*256 + ((sc<<1) ^ ((s&7)<<4))));
      }
      float yv[16];
      __builtin_amdgcn_s_setprio(1);
      if (sd == 0) {
        #pragma unroll
        for (int s = 0; s < 16; ++s) SCAN_STEP(s)
      } else {
        #pragma unroll
        for (int s = 15; s >= 0; --s) SCAN_STEP(s)
      }
      __builtin_amdgcn_s_setprio(0);
      u16* yrow = ysL + (chunk << 11) + sc;
      if (k <= 3) {
        #pragma unroll
        for (int s = 0; s < 16; ++s) yrow[s << 7] = f2bf(0.25f*yv[s]);
      } else {
        #pragma unroll
        for (int s = 0; s < 16; ++s) {
          float o = b2f(yrow[s << 7]);
          yrow[s << 7] = f2bf(o + 0.25f*yv[s]);
        }
      }
      __syncthreads();
    }
  } else {
    // ---------- heavy producer ----------
    int tbase = 8 + (wv & 1) * 12;
    short8 Af[12][4];
    #pragma unroll
    for (int ti = 0; ti < 12; ++ti)
      #pragma unroll
      for (int kk = 0; kk < 4; ++kk)
        Af[ti][kk] = *(const short8*)(Wf + (size_t)(((dw*32 + tbase + ti)*4 + kk)*64 + lane)*8);
    __syncthreads();                       // xs ready
    PRODUCE(12, 0, dw ? 7 : 0);
    __syncthreads();                       // cs[0] ready
    #pragma unroll 1
    for (int k = 0; k < 8; ++k) {
      if (k < 7) PRODUCE(12, (k+1)&1, dw ? (6-k) : (k+1));
      __syncthreads();
    }
  }

  // cooperative coalesced writeout: 2048 short8 slots
  #pragma unroll
  for (int r = 0; r < 4; ++r) {
    int slot = r*512 + t;
    int pos = slot >> 4, j = slot & 15;
    short8 v = *(const short8*)(ysL + (pos << 7) + (j << 3));
    size_t rowg = AXISW ? ((size_t)(b<<14) + (l<<7) + pos)
                        : ((size_t)(b<<14) + (pos<<7) + l);
    u16* op = fusedP + (rowg << 7) + (j << 3);
    if (PART) {
      short8 o = *(const short8*)op;
      short8 rr;
      #pragma unroll
      for (int i = 0; i < 8; ++i) rr[i] = (short)f2bf(b2f((u16)v[i]) + b2f((u16)o[i]));
      *(short8*)op = rr;
    } else {
      *(short8*)op = v;
    }
  }
}

// GroupNorm stats over bf16 channels-last.
__global__ __launch_bounds__(256) void gn_stats_bf(const u16* __restrict__ X,
    float* __restrict__ stats)
{
  int bg = blockIdx.x, chunk = blockIdx.y;
  int b = bg >> 4, g = bg & 15;
  int t = threadIdx.x;
  int c = t & 7, pr = t >> 3;
  const u16* base = X + ((size_t)b << 21) + (g << 3) + c;
  int p0 = chunk << 10;
  float s = 0.f, s2 = 0.f;
  for (int i = 0; i < 32; ++i) {
    float v = b2f(base[(size_t)(p0 + (i << 5) + pr) << 7]);
    s += v; s2 += v*v;
  }
  #pragma unroll
  for (int off = 32; off; off >>= 1) { s += __shfl_down(s, off); s2 += __shfl_down(s2, off); }
  __shared__ float ls[8];
  int wv = t >> 6, lane = t & 63;
  if (lane == 0) { ls[wv] = s; ls[4 + wv] = s2; }
  __syncthreads();
  if (t == 0) {
    atomicAdd(&stats[bg], ls[0]+ls[1]+ls[2]+ls[3]);
    atomicAdd(&stats[64+bg], ls[4]+ls[5]+ls[6]+ls[7]);
  }
}

// Apply GN1 + SiLU: read bf16, write bf16.
__global__ __launch_bounds__(256) void gn_apply(const u16* __restrict__ X,
    const float* __restrict__ stats, const float* __restrict__ gamma,
    const float* __restrict__ beta, u16* __restrict__ Xb)
{
  int i4 = blockIdx.x*256 + threadIdx.x;
  size_t base = (size_t)i4 << 2;
  int c4 = (int)(base & 127);
  size_t p = base >> 7;
  int b = (int)(p >> 14);
  int g = c4 >> 3;
  const float cnt = (float)(CPG*HW_);
  float mu = stats[b*16+g]/cnt;
  float var = stats[64+b*16+g]/cnt - mu*mu;
  float rs = rsqrtf(var + 1e-5f);
  ushort4 v = *(const ushort4*)(X + base);
  ushort4 o;
  o.x = f2bf(siluf_((b2f(v.x)-mu)*rs*gamma[c4+0]+beta[c4+0]));
  o.y = f2bf(siluf_((b2f(v.y)-mu)*rs*gamma[c4+1]+beta[c4+1]));
  o.z = f2bf(siluf_((b2f(v.z)-mu)*rs*gamma[c4+2]+beta[c4+2]));
  o.w = f2bf(siluf_((b2f(v.w)-mu)*rs*gamma[c4+3]+beta[c4+3]));
  *(ushort4*)(Xb + base) = o;
}

// Depthwise 3x3 with fused gate multiply: z = dw3x3(fused * gate), bf16 in/out.
__global__ __launch_bounds__(256) void dwconv(const u16* __restrict__ Z,
    const u16* __restrict__ G, const float* __restrict__ K9, u16* __restrict__ Outp)
{
  __shared__ float kk[1152];
  int t = threadIdx.x;
  for (int i = t; i < 1152; i += 256) kk[i] = K9[i];
  __syncthreads();
  int i4 = blockIdx.x*256 + t;
  size_t base = (size_t)i4 << 2;
  int c0 = (int)(base & 127);
  size_t p = base >> 7;
  int w = (int)(p & 127), h = (int)((p >> 7) & 127), b = (int)(p >> 14);
  float4 acc = make_float4(0.f,0.f,0.f,0.f);
  #pragma unroll
  for (int di = 0; di < 3; ++di) {
    int hy = h + di - 1;
    if ((unsigned)hy > 127u) continue;
    #pragma unroll
    for (int dj = 0; dj < 3; ++dj) {
      int wx = w + dj - 1;
      if ((unsigned)wx > 127u) continue;
      size_t p2 = ((size_t)b << 14) + (hy << 7) + wx;
      ushort4 zv = *(const ushort4*)(Z + (p2 << 7) + c0);
      ushort4 gv = *(const ushort4*)(G + (p2 << 7) + c0);
      int o = di*3 + dj;
      acc.x += b2f(zv.x) * b2f(gv.x) * kk[c0*9 + o];
      acc.y += b2f(zv.y) * b2f(gv.y) * kk[(c0+1)*9 + o];
      acc.z += b2f(zv.z) * b2f(gv.z) * kk[(c0+2)*9 + o];
      acc.w += b2f(zv.w) * b2f(gv.w) * kk[(c0+3)*9 + o];
    }
  }
  ushort4 ov;
  ov.x = f2bf(acc.x); ov.y = f2bf(acc.y); ov.z = f2bf(acc.z); ov.w = f2bf(acc.w);
  *(ushort4*)(Outp + base) = ov;
}

// GN2 apply + SiLU + transpose to channels-first fp32 output. Input bf16.
__global__ __launch_bounds__(256) void gn_final(const u16* __restrict__ Z,
    const float* __restrict__ stats, const float* __restrict__ gamma,
    const float* __restrict__ beta, float* __restrict__ out)
{
  __shared__ float ls[32][129];
  int w0 = blockIdx.x << 5, hh = blockIdx.y, b = blockIdx.z;
  size_t p0 = ((size_t)b << 14) + (hh << 7) + w0;
  int t = threadIdx.x;
  const float cnt = (float)(CPG*HW_);
  #pragma unroll
  for (int i = 0; i < 4; ++i) {
    int l = t + i*256;
    int row = l >> 5, c4 = (l & 31) << 2;
    ushort4 v = *(const ushort4*)(Z + ((p0 + row) << 7) + c4);
    int g = c4 >> 3;
    float mu = stats[b*16+g]/cnt;
    float var = stats[64+b*16+g]/cnt - mu*mu;
    float rs = rsqrtf(var + 1e-5f);
    float vals[4] = {b2f(v.x), b2f(v.y), b2f(v.z), b2f(v.w)};
    #pragma unroll
    for (int j = 0; j < 4; ++j) {
      float nv = (vals[j]-mu)*rs*gamma[c4+j] + beta[c4+j];
      ls[row][c4+j] = siluf_(nv);
    }
  }
  __syncthreads();
  int ww = t & 31, c0 = t >> 5;
  #pragma unroll
  for (int cc = c0; cc < 128; cc += 8) {
    out[(((size_t)(b*128 + cc)) << 14) + (hh << 7) + (w0 + ww)] = ls[ww][cc];
  }
}

extern "C" void kernel_launch(void* const* d_in, const int* in_sizes, int n_in,
                              void* d_out, int out_size, void* d_ws, size_t ws_size,
                              hipStream_t stream)
{
  (void)in_sizes; (void)n_in; (void)out_size; (void)ws_size;
  const float* x      = (const float*)d_in[0];
  const float* w_in   = (const float*)d_in[1];
  const float* g1g    = (const float*)d_in[2];
  const float* g1b    = (const float*)d_in[3];
  const float* w_gate = (const float*)d_in[4];
  const float* b_gate = (const float*)d_in[5];
  const float* dyn_w  = (const float*)d_in[6];
  const float* dyn_b  = (const float*)d_in[7];
  const float* dwk    = (const float*)d_in[8];
  const float* w_out  = (const float*)d_in[9];
  const float* g2g    = (const float*)d_in[10];
  const float* g2b    = (const float*)d_in[11];
  float* out = (float*)d_out;

  char* p = (char*)d_ws;
  u16*   xT     = (u16*)p;              p += (size_t)S_*2;   // x transposed bf16; later Zdw
  u16*   xpr    = (u16*)p;              p += (size_t)S_*2;   // xp_raw bf16; later Zout
  u16*   Abf    = (u16*)p;              p += (size_t)S_*2;   // xp (post GN1+SiLU) bf16
  u16*   fusedP = (u16*)p;              p += (size_t)S_*2;   // fused partial/final bf16
  u16*   Gbf    = (u16*)p;              p += (size_t)S_*2;   // gate bf16
  u16*   wfrag  = (u16*)p;              p += (size_t)262144*2;
  u16*   wgbf   = (u16*)p;              p += (size_t)16384*2;
  u16*   wobf   = (u16*)p;              p += (size_t)16384*2;
  u16*   wibf   = (u16*)p;              p += (size_t)16384*2;
  float* bperm  = (float*)p;            p += (size_t)2048*4;
  float* stats  = (float*)p;            p += (size_t)256*4;
  u16*   Zdw    = xT;                   // alias (xT dead after in_proj)
  u16*   Zout   = xpr;                  // alias (xp_raw dead after gn_apply)

  prep_kernel<<<1225, 256, 0, stream>>>(dyn_w, dyn_b, w_gate, w_out, w_in,
                                        wfrag, bperm, wgbf, wobf, wibf, stats);
  xpose<<<dim3(512, 4), 256, 0, stream>>>(x, xT);
  mfma_nt128<0,0><<<1024, 256, 0, stream>>>(xT, wibf, nullptr, xpr);
  gn_stats_bf<<<dim3(64, 16), 256, 0, stream>>>(xpr, stats);
  gn_apply<<<8192, 256, 0, stream>>>(xpr, stats, g1g, g1b, Abf);

  scan_fused<1,0><<<512, 512, 0, stream>>>(Abf, wfrag, bperm, fusedP);
  scan_fused<0,1><<<512, 512, 0, stream>>>(Abf, wfrag + 131072, bperm + 1024, fusedP);

  mfma_nt128<1,1><<<1024, 256, 0, stream>>>(Abf, wgbf, b_gate, Gbf);
  dwconv<<<8192, 256, 0, stream>>>(fusedP, Gbf, dwk, Zdw);
  mfma_nt128<0,0><<<1024, 256, 0, stream>>>(Zdw, wobf, nullptr, Zout);
  gn_stats_bf<<<dim3(64, 16), 256, 0, stream>>>(Zout, stats + 128);
  gn_final<<<dim3(4, 128, 4), 256, 0, stream>>>(Zout, stats + 128, g2g, g2b, out);
}

// Round 9
// 199.073 us; speedup vs baseline: 1.3040x; 1.1867x over previous
//
#include <hip/hip_runtime.h>
#include <math.h>

#define B_ 4
#define C_ 128
#define HW_ 16384
#define P_ 65536
#define S_ 8388608   // B*C*H*W elements
#define CPG 8        // channels per group (128/16)

typedef unsigned short u16;
typedef __attribute__((ext_vector_type(8))) short short8;
typedef __attribute__((ext_vector_type(4))) float f32x4;

__device__ __forceinline__ float sigmoidf_(float x){ return 1.f/(1.f+__expf(-x)); }
__device__ __forceinline__ float siluf_(float x){ return x*sigmoidf_(x); }
__device__ __forceinline__ u16 f2bf(float f){
  unsigned x = __float_as_uint(f);
  return (u16)((x + 0x7fffu + ((x >> 16) & 1u)) >> 16);
}
__device__ __forceinline__ float b2f(u16 u){ return __uint_as_float(((unsigned)u) << 16); }

// Build wfrag (dyn_w in MFMA A-fragment order), bperm, wgbf, wobf, wibf, stats=0.
__global__ __launch_bounds__(256) void prep_kernel(const float* __restrict__ dyn_w,
    const float* __restrict__ dyn_b, const float* __restrict__ w_gate,
    const float* __restrict__ w_out, const float* __restrict__ w_in,
    u16* __restrict__ wfrag, float* __restrict__ bperm, u16* __restrict__ wgbf,
    u16* __restrict__ wobf, u16* __restrict__ wibf, float* __restrict__ stats)
{
  int idx = blockIdx.x*256 + threadIdx.x;
  if (idx < 262144) {
    int e = idx & 7, lane = (idx >> 3) & 63, kk = (idx >> 9) & 3;
    int ct = (idx >> 11) & 31, d = idx >> 16;
    int m = lane & 15, kg = lane >> 4;
    int col = ct*16 + m;
    int c = col >> 2, f = col & 3;
    int k = kk*32 + kg*8 + e;
    wfrag[idx] = f2bf(dyn_w[(size_t)((d*512) + f*128 + c)*128 + k]);
  } else if (idx < 264192) {
    int i2 = idx - 262144;
    int op = i2 & 511, d = i2 >> 9;
    bperm[i2] = dyn_b[d*512 + (op & 3)*128 + (op >> 2)];
  } else if (idx < 280576) {
    wgbf[idx - 264192] = f2bf(w_gate[idx - 264192]);
  } else if (idx < 296960) {
    wobf[idx - 280576] = f2bf(w_out[idx - 280576]);
  } else if (idx < 313344) {
    wibf[idx - 296960] = f2bf(w_in[idx - 296960]);
  } else if (idx < 313600) {
    stats[idx - 313344] = 0.f;
  }
}

// in_proj MFMA GEMM reading channels-first fp32 x directly.
// x [B][128][16384] fp32, Wm=wibf [128][128] bf16, Out bf16 [P][128] channels-last.
// Grid: P/64 = 1024 blocks; block 256 thr / 4 waves; wave w = cols 32w..32w+31.
__global__ __launch_bounds__(256) void mfma_inproj(const float* __restrict__ x,
    const u16* __restrict__ Wm, u16* __restrict__ Out)
{
  __shared__ __align__(16) u16 st[64*136];
  int t = threadIdx.x;
  int wv = t >> 6, lane = t & 63;
  int m = lane & 15, kg = lane >> 4;
  int pt = blockIdx.x << 6;                // global output row
  int b = blockIdx.x >> 8;                 // 256 blocks per batch
  int hw0 = (blockIdx.x & 255) << 6;
  const float* xb = x + ((size_t)b << 21);

  // A fragments: Af[rt][kk][e] = bf16(x[b][kk*32+kg*8+e][hw0+rt*16+m]).
  // For fixed (kk,e), 16 consecutive lanes read consecutive positions -> 64B segments.
  short8 Af[4][4];
  #pragma unroll
  for (int rt = 0; rt < 4; ++rt) {
    int pos = hw0 + rt*16 + m;
    #pragma unroll
    for (int kk = 0; kk < 4; ++kk) {
      short8 f;
      #pragma unroll
      for (int e = 0; e < 8; ++e)
        f[e] = (short)f2bf(xb[(size_t)(kk*32 + kg*8 + e)*HW_ + pos]);
      Af[rt][kk] = f;
    }
  }
  #pragma unroll
  for (int ct2 = 0; ct2 < 2; ++ct2) {
    int ot = wv*32 + ct2*16;
    const u16* wr = Wm + ((size_t)(ot + m) << 7) + kg*8;
    short8 Bf[4];
    #pragma unroll
    for (int kk = 0; kk < 4; ++kk)
      Bf[kk] = *(const short8*)(wr + kk*32);
    f32x4 acc[4];
    #pragma unroll
    for (int rt = 0; rt < 4; ++rt) acc[rt] = (f32x4){0.f,0.f,0.f,0.f};
    #pragma unroll
    for (int rt = 0; rt < 4; ++rt)
      #pragma unroll
      for (int kk = 0; kk < 4; ++kk)
        acc[rt] = __builtin_amdgcn_mfma_f32_16x16x32_bf16(Af[rt][kk], Bf[kk], acc[rt], 0, 0, 0);
    #pragma unroll
    for (int rt = 0; rt < 4; ++rt) {
      #pragma unroll
      for (int r = 0; r < 4; ++r)
        st[(rt*16 + kg*4 + r)*136 + ot + m] = f2bf(acc[rt][r]);
    }
  }
  __syncthreads();
  #pragma unroll
  for (int i = 0; i < 4; ++i) {
    int slot = i*256 + t;
    int row = slot >> 4, j = slot & 15;
    short8 v = *(const short8*)(st + row*136 + (j << 3));
    *(short8*)(Out + ((size_t)(pt + row) << 7) + (j << 3)) = v;
  }
}

// MFMA NT GEMM, O=128, LDS-staged coalesced output (r7-proven version).
template<int BIAS, int SIG>
__global__ __launch_bounds__(256) void mfma_nt128(const u16* __restrict__ X,
    const u16* __restrict__ Wm, const float* __restrict__ bias, u16* __restrict__ Out)
{
  __shared__ __align__(16) u16 st[64*136];
  int t = threadIdx.x;
  int wv = t >> 6, lane = t & 63;
  int m = lane & 15, kg = lane >> 4;
  int pt = blockIdx.x << 6;

  short8 Af[4][4];
  #pragma unroll
  for (int rt = 0; rt < 4; ++rt) {
    const u16* ar = X + ((size_t)(pt + rt*16 + m) << 7) + kg*8;
    #pragma unroll
    for (int kk = 0; kk < 4; ++kk)
      Af[rt][kk] = *(const short8*)(ar + kk*32);
  }
  #pragma unroll
  for (int ct2 = 0; ct2 < 2; ++ct2) {
    int ot = wv*32 + ct2*16;
    const u16* wr = Wm + ((size_t)(ot + m) << 7) + kg*8;
    short8 Bf[4];
    #pragma unroll
    for (int kk = 0; kk < 4; ++kk)
      Bf[kk] = *(const short8*)(wr + kk*32);
    f32x4 acc[4];
    #pragma unroll
    for (int rt = 0; rt < 4; ++rt) acc[rt] = (f32x4){0.f,0.f,0.f,0.f};
    #pragma unroll
    for (int rt = 0; rt < 4; ++rt)
      #pragma unroll
      for (int kk = 0; kk < 4; ++kk)
        acc[rt] = __builtin_amdgcn_mfma_f32_16x16x32_bf16(Af[rt][kk], Bf[kk], acc[rt], 0, 0, 0);
    float bv = BIAS ? bias[ot + m] : 0.f;
    #pragma unroll
    for (int rt = 0; rt < 4; ++rt) {
      #pragma unroll
      for (int r = 0; r < 4; ++r) {
        float v = acc[rt][r] + bv;
        if (SIG) v = sigmoidf_(v);
        st[(rt*16 + kg*4 + r)*136 + ot + m] = f2bf(v);
      }
    }
  }
  __syncthreads();
  #pragma unroll
  for (int i = 0; i < 4; ++i) {
    int slot = i*256 + t;
    int row = slot >> 4, j = slot & 15;
    short8 v = *(const short8*)(st + row*136 + (j << 3));
    *(short8*)(Out + ((size_t)(pt + row) << 7) + (j << 3)) = v;
  }
}

// Produce 16-pos coeff chunk into cs double buffer (bank-swizzled).
#define PRODUCE(NT, bufv, chunkv)  do { \
  int posg_ = (chunkv)*16 + m; int swp_ = (posg_ & 7) << 4; \
  short8 Bfr[4]; \
  _Pragma("unroll") for (int kk = 0; kk < 4; ++kk) \
    Bfr[kk] = *(const short8*)((char*)xs + posg_*256 + (((kk<<6)+(kg<<4)) ^ swp_)); \
  _Pragma("unroll") for (int ti = 0; ti < NT; ++ti) { \
    f32x4 acc = (f32x4){0.f,0.f,0.f,0.f}; \
    _Pragma("unroll") for (int kk = 0; kk < 4; ++kk) \
      acc = __builtin_amdgcn_mfma_f32_16x16x32_bf16(Af[ti][kk], Bfr[kk], acc, 0, 0, 0); \
    int colL_ = (tbase + ti)*16 + (kg<<2); \
    unsigned lo_ = (unsigned)f2bf(acc[0]) | ((unsigned)f2bf(acc[1])<<16); \
    unsigned hi_ = (unsigned)f2bf(acc[2]) | ((unsigned)f2bf(acc[3])<<16); \
    int byte_ = (((bufv)*2 + dw)<<14) + (m<<10) + ((colL_<<1) ^ ((m&7)<<4)); \
    *(uint2*)((char*)cs + byte_) = make_uint2(lo_, hi_); \
  } } while(0)

#define SCAN_STEP(s) { \
  float ar = b2f((u16)(cw[s].x & 0xffffu)) + bv.x; \
  float br = b2f((u16)(cw[s].x >> 16)) + bv.y; \
  float cr = b2f((u16)(cw[s].y & 0xffffu)) + bv.z; \
  float dr = b2f((u16)(cw[s].y >> 16)) + bv.w; \
  float aa = sigmoidf_(ar); \
  h = aa*h + br*xf[s]; \
  yv[s] = cr*h + dr*xf[s]; }

// Fused coeff-GEMM + bidirectional scan (r7-proven version).
// Block = 512 thr (8 waves): waves 0-3 = scanners (+4 W-tiles); waves 4-7 =
// producers (12 W-tiles). cs double-buffered, y accumulated in LDS.
template<int AXISW, int PART>
__global__ __launch_bounds__(512, 2) void scan_fused(const u16* __restrict__ Abf,
    const u16* __restrict__ Wf, const float* __restrict__ bias,
    u16* __restrict__ fusedP)
{
  __shared__ __align__(16) u16 xs[128*128];      // 32 KB, swizzled byte ^ ((pos&7)<<4)
  __shared__ __align__(16) u16 cs[2][2][16*512]; // 64 KB: [buf][dir][16 pos][512 cols]
  __shared__ __align__(16) u16 ysL[128*128];     // 32 KB bf16 partial y [pos][ch]
  int line = blockIdx.x;
  int b = line >> 7, l = line & 127;
  int t = threadIdx.x;
  int wv = t >> 6, lane = t & 63;
  int m = lane & 15, kg = lane >> 4;
  int dw = (wv >> 1) & 1;    // this wave's coeff direction

  // stage xp tile for the line (128 pos x 128 ch)
  #pragma unroll
  for (int i = 0; i < 4; ++i) {
    int idx = i*512 + t;
    int pos = idx >> 4, j = idx & 15;
    size_t row = AXISW ? ((size_t)(b<<14) + (l<<7) + pos)
                       : ((size_t)(b<<14) + (pos<<7) + l);
    short8 v = *(const short8*)(Abf + (row<<7) + (j<<3));
    int byte = pos*256 + ((j*16) ^ ((pos&7)<<4));
    *(short8*)((char*)xs + byte) = v;
  }

  if (wv < 4) {
    // ---------- scanner + light producer ----------
    int tbase = (wv & 1) * 4;
    short8 Af[4][4];
    #pragma unroll
    for (int ti = 0; ti < 4; ++ti)
      #pragma unroll
      for (int kk = 0; kk < 4; ++kk)
        Af[ti][kk] = *(const short8*)(Wf + (size_t)(((dw*32 + tbase + ti)*4 + kk)*64 + lane)*8);
    __syncthreads();                       // xs ready
    PRODUCE(4, 0, dw ? 7 : 0);
    __syncthreads();                       // cs[0] ready

    int sd = dw;
    int sc = ((wv & 1) << 6) + lane;       // scan channel 0..127
    float4 bv = *(const float4*)(bias + (sd << 9) + (sc << 2));
    float h = 0.f;

    #pragma unroll 1
    for (int k = 0; k < 8; ++k) {
      if (k < 7) PRODUCE(4, (k+1)&1, dw ? (6-k) : (k+1));
      int chunk = sd ? (7-k) : k;
      int csb = (((k&1)*2 + sd) << 14);
      uint2 cw[16];
      #pragma unroll
      for (int s = 0; s < 16; ++s)
        cw[s] = *(const uint2*)((char*)cs + csb + (s<<10) + ((sc<<3) ^ ((s&7)<<4)));
      float xf[16];
      #pragma unroll
      for (int s = 0; s < 16; ++s) {
        int pos = (chunk<<4) + s;
        xf[s] = b2f(*(const u16*)((char*)xs + pos*256 + ((sc<<1) ^ ((s&7)<<4))));
      }
      float yv[16];
      __builtin_amdgcn_s_setprio(1);
      if (sd == 0) {
        #pragma unroll
        for (int s = 0; s < 16; ++s) SCAN_STEP(s)
      } else {
        #pragma unroll
        for (int s = 15; s >= 0; --s) SCAN_STEP(s)
      }
      __builtin_amdgcn_s_setprio(0);
      u16* yrow = ysL + (chunk << 11) + sc;
      if (k <= 3) {
        #pragma unroll
        for (int s = 0; s < 16; ++s) yrow[s << 7] = f2bf(0.25f*yv[s]);
      } else {
        #pragma unroll
        for (int s = 0; s < 16; ++s) {
          float o = b2f(yrow[s << 7]);
          yrow[s << 7] = f2bf(o + 0.25f*yv[s]);
        }
      }
      __syncthreads();
    }
  } else {
    // ---------- heavy producer ----------
    int tbase = 8 + (wv & 1) * 12;
    short8 Af[12][4];
    #pragma unroll
    for (int ti = 0; ti < 12; ++ti)
      #pragma unroll
      for (int kk = 0; kk < 4; ++kk)
        Af[ti][kk] = *(const short8*)(Wf + (size_t)(((dw*32 + tbase + ti)*4 + kk)*64 + lane)*8);
    __syncthreads();                       // xs ready
    PRODUCE(12, 0, dw ? 7 : 0);
    __syncthreads();                       // cs[0] ready
    #pragma unroll 1
    for (int k = 0; k < 8; ++k) {
      if (k < 7) PRODUCE(12, (k+1)&1, dw ? (6-k) : (k+1));
      __syncthreads();
    }
  }

  // cooperative coalesced writeout: 2048 short8 slots
  #pragma unroll
  for (int r = 0; r < 4; ++r) {
    int slot = r*512 + t;
    int pos = slot >> 4, j = slot & 15;
    short8 v = *(const short8*)(ysL + (pos << 7) + (j << 3));
    size_t rowg = AXISW ? ((size_t)(b<<14) + (l<<7) + pos)
                        : ((size_t)(b<<14) + (pos<<7) + l);
    u16* op = fusedP + (rowg << 7) + (j << 3);
    if (PART) {
      short8 o = *(const short8*)op;
      short8 rr;
      #pragma unroll
      for (int i = 0; i < 8; ++i) rr[i] = (short)f2bf(b2f((u16)v[i]) + b2f((u16)o[i]));
      *(short8*)op = rr;
    } else {
      *(short8*)op = v;
    }
  }
}

// GroupNorm stats over bf16 channels-last, coalesced short8 loads.
// Grid (4 batches, 64 chunks); thread t's channel group = t&15 (constant).
__global__ __launch_bounds__(256) void gn_stats_bf(const u16* __restrict__ X,
    float* __restrict__ stats)
{
  int b = blockIdx.x, chunk = blockIdx.y;
  const u16* base = X + ((size_t)b << 21) + ((size_t)chunk << 15);
  int t = threadIdx.x;
  float s = 0.f, q = 0.f;
  #pragma unroll 4
  for (int it = 0; it < 16; ++it) {
    short8 v = *(const short8*)(base + it*2048 + t*8);
    #pragma unroll
    for (int e = 0; e < 8; ++e) { float f = b2f((u16)v[e]); s += f; q += f*f; }
  }
  s += __shfl_xor(s, 16); q += __shfl_xor(q, 16);
  s += __shfl_xor(s, 32); q += __shfl_xor(q, 32);
  __shared__ float sg[32];
  if (t < 32) sg[t] = 0.f;
  __syncthreads();
  int lane = t & 63;
  if (lane < 16) { atomicAdd(&sg[lane], s); atomicAdd(&sg[16 + lane], q); }
  __syncthreads();
  if (t < 16) atomicAdd(&stats[b*16 + t], sg[t]);
  else if (t < 32) atomicAdd(&stats[64 + b*16 + (t - 16)], sg[t]);
}

// Apply GN1 + SiLU: read bf16, write bf16.
__global__ __launch_bounds__(256) void gn_apply(const u16* __restrict__ X,
    const float* __restrict__ stats, const float* __restrict__ gamma,
    const float* __restrict__ beta, u16* __restrict__ Xb)
{
  int i4 = blockIdx.x*256 + threadIdx.x;
  size_t base = (size_t)i4 << 2;
  int c4 = (int)(base & 127);
  size_t p = base >> 7;
  int b = (int)(p >> 14);
  int g = c4 >> 3;
  const float cnt = (float)(CPG*HW_);
  float mu = stats[b*16+g]/cnt;
  float var = stats[64+b*16+g]/cnt - mu*mu;
  float rs = rsqrtf(var + 1e-5f);
  ushort4 v = *(const ushort4*)(X + base);
  ushort4 o;
  o.x = f2bf(siluf_((b2f(v.x)-mu)*rs*gamma[c4+0]+beta[c4+0]));
  o.y = f2bf(siluf_((b2f(v.y)-mu)*rs*gamma[c4+1]+beta[c4+1]));
  o.z = f2bf(siluf_((b2f(v.z)-mu)*rs*gamma[c4+2]+beta[c4+2]));
  o.w = f2bf(siluf_((b2f(v.w)-mu)*rs*gamma[c4+3]+beta[c4+3]));
  *(ushort4*)(Xb + base) = o;
}

// Depthwise 3x3 with fused gate multiply: z = dw3x3(fused * gate), bf16 in/out.
__global__ __launch_bounds__(256) void dwconv(const u16* __restrict__ Z,
    const u16* __restrict__ G, const float* __restrict__ K9, u16* __restrict__ Outp)
{
  __shared__ float kk[1152];
  int t = threadIdx.x;
  for (int i = t; i < 1152; i += 256) kk[i] = K9[i];
  __syncthreads();
  int i4 = blockIdx.x*256 + t;
  size_t base = (size_t)i4 << 2;
  int c0 = (int)(base & 127);
  size_t p = base >> 7;
  int w = (int)(p & 127), h = (int)((p >> 7) & 127), b = (int)(p >> 14);
  float4 acc = make_float4(0.f,0.f,0.f,0.f);
  #pragma unroll
  for (int di = 0; di < 3; ++di) {
    int hy = h + di - 1;
    if ((unsigned)hy > 127u) continue;
    #pragma unroll
    for (int dj = 0; dj < 3; ++dj) {
      int wx = w + dj - 1;
      if ((unsigned)wx > 127u) continue;
      size_t p2 = ((size_t)b << 14) + (hy << 7) + wx;
      ushort4 zv = *(const ushort4*)(Z + (p2 << 7) + c0);
      ushort4 gv = *(const ushort4*)(G + (p2 << 7) + c0);
      int o = di*3 + dj;
      acc.x += b2f(zv.x) * b2f(gv.x) * kk[c0*9 + o];
      acc.y += b2f(zv.y) * b2f(gv.y) * kk[(c0+1)*9 + o];
      acc.z += b2f(zv.z) * b2f(gv.z) * kk[(c0+2)*9 + o];
      acc.w += b2f(zv.w) * b2f(gv.w) * kk[(c0+3)*9 + o];
    }
  }
  ushort4 ov;
  ov.x = f2bf(acc.x); ov.y = f2bf(acc.y); ov.z = f2bf(acc.z); ov.w = f2bf(acc.w);
  *(ushort4*)(Outp + base) = ov;
}

// GN2 apply + SiLU + transpose to channels-first fp32 output. Input bf16.
__global__ __launch_bounds__(256) void gn_final(const u16* __restrict__ Z,
    const float* __restrict__ stats, const float* __restrict__ gamma,
    const float* __restrict__ beta, float* __restrict__ out)
{
  __shared__ float ls[32][129];
  int w0 = blockIdx.x << 5, hh = blockIdx.y, b = blockIdx.z;
  size_t p0 = ((size_t)b << 14) + (hh << 7) + w0;
  int t = threadIdx.x;
  const float cnt = (float)(CPG*HW_);
  #pragma unroll
  for (int i = 0; i < 4; ++i) {
    int l = t + i*256;
    int row = l >> 5, c4 = (l & 31) << 2;
    ushort4 v = *(const ushort4*)(Z + ((p0 + row) << 7) + c4);
    int g = c4 >> 3;
    float mu = stats[b*16+g]/cnt;
    float var = stats[64+b*16+g]/cnt - mu*mu;
    float rs = rsqrtf(var + 1e-5f);
    float vals[4] = {b2f(v.x), b2f(v.y), b2f(v.z), b2f(v.w)};
    #pragma unroll
    for (int j = 0; j < 4; ++j) {
      float nv = (vals[j]-mu)*rs*gamma[c4+j] + beta[c4+j];
      ls[row][c4+j] = siluf_(nv);
    }
  }
  __syncthreads();
  int ww = t & 31, c0 = t >> 5;
  #pragma unroll
  for (int cc = c0; cc < 128; cc += 8) {
    out[(((size_t)(b*128 + cc)) << 14) + (hh << 7) + (w0 + ww)] = ls[ww][cc];
  }
}

extern "C" void kernel_launch(void* const* d_in, const int* in_sizes, int n_in,
                              void* d_out, int out_size, void* d_ws, size_t ws_size,
                              hipStream_t stream)
{
  (void)in_sizes; (void)n_in; (void)out_size; (void)ws_size;
  const float* x      = (const float*)d_in[0];
  const float* w_in   = (const float*)d_in[1];
  const float* g1g    = (const float*)d_in[2];
  const float* g1b    = (const float*)d_in[3];
  const float* w_gate = (const float*)d_in[4];
  const float* b_gate = (const float*)d_in[5];
  const float* dyn_w  = (const float*)d_in[6];
  const float* dyn_b  = (const float*)d_in[7];
  const float* dwk    = (const float*)d_in[8];
  const float* w_out  = (const float*)d_in[9];
  const float* g2g    = (const float*)d_in[10];
  const float* g2b    = (const float*)d_in[11];
  float* out = (float*)d_out;

  char* p = (char*)d_ws;
  u16*   Zbuf   = (u16*)p;              p += (size_t)S_*2;   // scratch for Zdw
  u16*   xpr    = (u16*)p;              p += (size_t)S_*2;   // xp_raw bf16; later Zout
  u16*   Abf    = (u16*)p;              p += (size_t)S_*2;   // xp (post GN1+SiLU) bf16
  u16*   fusedP = (u16*)p;              p += (size_t)S_*2;   // fused partial/final bf16
  u16*   Gbf    = (u16*)p;              p += (size_t)S_*2;   // gate bf16
  u16*   wfrag  = (u16*)p;              p += (size_t)262144*2;
  u16*   wgbf   = (u16*)p;              p += (size_t)16384*2;
  u16*   wobf   = (u16*)p;              p += (size_t)16384*2;
  u16*   wibf   = (u16*)p;              p += (size_t)16384*2;
  float* bperm  = (float*)p;            p += (size_t)2048*4;
  float* stats  = (float*)p;            p += (size_t)256*4;
  u16*   Zdw    = Zbuf;
  u16*   Zout   = xpr;                  // alias (xp_raw dead after gn_apply)

  prep_kernel<<<1225, 256, 0, stream>>>(dyn_w, dyn_b, w_gate, w_out, w_in,
                                        wfrag, bperm, wgbf, wobf, wibf, stats);
  mfma_inproj<<<1024, 256, 0, stream>>>(x, wibf, xpr);
  gn_stats_bf<<<dim3(4, 64), 256, 0, stream>>>(xpr, stats);
  gn_apply<<<8192, 256, 0, stream>>>(xpr, stats, g1g, g1b, Abf);

  scan_fused<1,0><<<512, 512, 0, stream>>>(Abf, wfrag, bperm, fusedP);
  scan_fused<0,1><<<512, 512, 0, stream>>>(Abf, wfrag + 131072, bperm + 1024, fusedP);

  mfma_nt128<1,1><<<1024, 256, 0, stream>>>(Abf, wgbf, b_gate, Gbf);
  dwconv<<<8192, 256, 0, stream>>>(fusedP, Gbf, dwk, Zdw);
  mfma_nt128<0,0><<<1024, 256, 0, stream>>>(Zdw, wobf, nullptr, Zout);
  gn_stats_bf<<<dim3(4, 64), 256, 0, stream>>>(Zout, stats + 128);
  gn_final<<<dim3(4, 128, 4), 256, 0, stream>>>(Zout, stats + 128, g2g, g2b, out);
}